// Round 1
// baseline (2271.381 us; speedup 1.0000x reference)
//
#include <hip/hip_runtime.h>
#include <hip/hip_bf16.h>
#include <stdint.h>

#define BB 2
#define SS 4096
#define HH 1024
#define NHh 16
#define HD 64
#define LL 64
#define BS 64
#define RR 3
#define PENf (-10000.0f)

typedef unsigned int uint;

__device__ __forceinline__ float bflo(uint u) { return __uint_as_float(u << 16); }
__device__ __forceinline__ float bfhi(uint u) { return __uint_as_float(u & 0xffff0000u); }

__device__ __forceinline__ void unpack8(uint4 w, float* dst, float scale) {
    dst[0] = bflo(w.x) * scale; dst[1] = bfhi(w.x) * scale;
    dst[2] = bflo(w.y) * scale; dst[3] = bfhi(w.y) * scale;
    dst[4] = bflo(w.z) * scale; dst[5] = bfhi(w.z) * scale;
    dst[6] = bflo(w.w) * scale; dst[7] = bfhi(w.w) * scale;
}

__device__ __forceinline__ float4 fma4(float a, float4 b, float4 c) {
    c.x = fmaf(a, b.x, c.x); c.y = fmaf(a, b.y, c.y);
    c.z = fmaf(a, b.z, c.z); c.w = fmaf(a, b.w, c.w);
    return c;
}

// ---------------- projection GEMM ----------------
// X: [8192][1024] f32 row-major (Q/K/V flattened), W: [1024][1024] f32 row-major,
// out[m][n] = sum_k X[m][k]*W[n][k] + bias[n], written bf16 to [B][NH][S][HD].
__global__ __launch_bounds__(256)
void proj_kernel(const float* __restrict__ X, const float* __restrict__ W,
                 const float* __restrict__ bias, __hip_bfloat16* __restrict__ out)
{
    __shared__ __align__(16) float As[16][68];
    __shared__ __align__(16) float Bs[16][68];
    const int tid = threadIdx.x;
    const int m0 = blockIdx.x * 64;
    const int n0 = blockIdx.y * 64;
    const int tx = tid & 15, ty = tid >> 4;
    const int lr = tid >> 2, lc = (tid & 3) << 2;

    float acc[4][4];
#pragma unroll
    for (int i = 0; i < 4; ++i)
#pragma unroll
        for (int j = 0; j < 4; ++j) acc[i][j] = 0.0f;

    const float* xp = X + (size_t)(m0 + lr) * HH + lc;
    const float* wp = W + (size_t)(n0 + lr) * HH + lc;

    for (int k0 = 0; k0 < HH; k0 += 16) {
        float4 a = *(const float4*)(xp + k0);
        float4 w = *(const float4*)(wp + k0);
        __syncthreads();
        As[lc + 0][lr] = a.x; As[lc + 1][lr] = a.y; As[lc + 2][lr] = a.z; As[lc + 3][lr] = a.w;
        Bs[lc + 0][lr] = w.x; Bs[lc + 1][lr] = w.y; Bs[lc + 2][lr] = w.z; Bs[lc + 3][lr] = w.w;
        __syncthreads();
#pragma unroll
        for (int kk = 0; kk < 16; ++kk) {
            float4 av = *(const float4*)&As[kk][ty * 4];
            float4 bv = *(const float4*)&Bs[kk][tx * 4];
            float aarr[4] = {av.x, av.y, av.z, av.w};
            float barr[4] = {bv.x, bv.y, bv.z, bv.w};
#pragma unroll
            for (int i = 0; i < 4; ++i)
#pragma unroll
                for (int j = 0; j < 4; ++j)
                    acc[i][j] = fmaf(aarr[i], barr[j], acc[i][j]);
        }
    }

#pragma unroll
    for (int i = 0; i < 4; ++i) {
        const int m = m0 + ty * 4 + i;
        const int b = m >> 12;
        const int s = m & 4095;
#pragma unroll
        for (int j = 0; j < 4; ++j) {
            const int n = n0 + tx * 4 + j;
            const float v = acc[i][j] + bias[n];
            const int nh = n >> 6, hd = n & 63;
            out[(((size_t)((b << 4) | nh) * SS) + s) * HD + hd] = __float2bfloat16(v);
        }
    }
}

// ---------------- block-sparse attention ----------------
// q/k/v: bf16 [B][NH][S][HD].  out: f32 [B][S][H].
__global__ __launch_bounds__(256)
void attn_kernel(const __hip_bfloat16* __restrict__ qg,
                 const __hip_bfloat16* __restrict__ kg,
                 const __hip_bfloat16* __restrict__ vg,
                 const float* __restrict__ mask,
                 const int* __restrict__ rand_attn,
                 float* __restrict__ out)
{
    __shared__ __align__(16) float qs[64][68];
    __shared__ __align__(16) float ks[64][68];
    __shared__ __align__(16) float vs[64][68];
    __shared__ __align__(16) float ps[64][68];  // p transposed: [kc][qrow]
    __shared__ float alpha_row[64];
    __shared__ float l_row[64];
    __shared__ float kmask[64];

    const int tid = threadIdx.x;
    const int bid = blockIdx.x;
    const int i = bid & 63;            // query block index
    const int h = (bid >> 6) & 15;
    const int b = bid >> 10;
    const int bh = (b << 4) | h;

    const int tq = tid >> 4;   // 0..15
    const int tk = tid & 15;   // 0..15

    // load q tile, fold in 1/sqrt(HD)
    {
        const int row = tid >> 2;
        const int c0 = (tid & 3) << 4;
        const uint4* src = (const uint4*)(qg + (((size_t)bh * SS) + (size_t)i * BS + row) * HD + c0);
        uint4 w0 = src[0];
        uint4 w1 = src[1];
        unpack8(w0, &qs[row][c0], 0.125f);
        unpack8(w1, &qs[row][c0 + 8], 0.125f);
    }

    // build key-block list
    int nkb;
    int kbl[8] = {0, 0, 0, 0, 0, 0, 0, 0};
    int pfl[8] = {0, 0, 0, 0, 0, 0, 0, 0};
    const bool dense = (i == 0) || (i == LL - 1);
    if (dense) {
        nkb = LL;
    } else {
        const int* ra = rand_attn + ((size_t)h * (LL - 2) + (i - 1)) * RR;
        if (i == 1) {
            kbl[0] = 0; kbl[1] = 1; kbl[2] = 2; kbl[3] = LL - 1;
            kbl[4] = ra[0]; kbl[5] = ra[1]; kbl[6] = ra[2];
            pfl[4] = pfl[5] = pfl[6] = 1;
            nkb = 7;
        } else if (i == LL - 2) {
            kbl[0] = 0; kbl[1] = LL - 3; kbl[2] = LL - 2; kbl[3] = LL - 1;
            kbl[4] = ra[0]; kbl[5] = ra[1]; kbl[6] = ra[2];
            pfl[4] = pfl[5] = pfl[6] = 1;
            nkb = 7;
        } else {
            kbl[0] = 0;            pfl[0] = 0;
            kbl[1] = i - 1;        pfl[1] = 1;
            kbl[2] = i;            pfl[2] = 1;
            kbl[3] = i + 1;        pfl[3] = 1;
            kbl[4] = LL - 1;       pfl[4] = 0;
            kbl[5] = ra[0]; kbl[6] = ra[1]; kbl[7] = ra[2];
            pfl[5] = pfl[6] = pfl[7] = 1;
            nkb = 8;
        }
    }

    // query-row masks for product penalties (rows tq + 16*ii)
    float qm[4];
#pragma unroll
    for (int ii = 0; ii < 4; ++ii)
        qm[ii] = mask[(size_t)b * SS + (size_t)i * BS + (tq + 16 * ii)];

    float mrow[4], lrow[4];
#pragma unroll
    for (int ii = 0; ii < 4; ++ii) { mrow[ii] = -1e30f; lrow[ii] = 0.0f; }

    float4 accv[4];
#pragma unroll
    for (int ii = 0; ii < 4; ++ii) accv[ii] = make_float4(0.f, 0.f, 0.f, 0.f);

    for (int it = 0; it < nkb; ++it) {
        const int kb = dense ? it : kbl[it];
        const int pf = dense ? 0 : pfl[it];

        __syncthreads();  // previous PV done before overwriting ks/vs/ps
        {
            const int row = tid >> 2;
            const int c0 = (tid & 3) << 4;
            const size_t base = (((size_t)bh * SS) + (size_t)kb * BS + row) * HD + c0;
            const uint4* srck = (const uint4*)(kg + base);
            uint4 k0w = srck[0];
            uint4 k1w = srck[1];
            const uint4* srcv = (const uint4*)(vg + base);
            uint4 v0w = srcv[0];
            uint4 v1w = srcv[1];
            unpack8(k0w, &ks[row][c0], 1.0f);
            unpack8(k1w, &ks[row][c0 + 8], 1.0f);
            unpack8(v0w, &vs[row][c0], 1.0f);
            unpack8(v1w, &vs[row][c0 + 8], 1.0f);
            if (tid < 64) kmask[tid] = mask[(size_t)b * SS + (size_t)kb * BS + tid];
        }
        __syncthreads();

        // scores: rows (tq+16*ii) x cols (tk+16*jj)
        float s[4][4];
#pragma unroll
        for (int ii = 0; ii < 4; ++ii)
#pragma unroll
            for (int jj = 0; jj < 4; ++jj) s[ii][jj] = 0.0f;

#pragma unroll
        for (int d0 = 0; d0 < HD; d0 += 4) {
            float4 qv[4], kv[4];
#pragma unroll
            for (int ii = 0; ii < 4; ++ii) qv[ii] = *(const float4*)&qs[tq + 16 * ii][d0];
#pragma unroll
            for (int jj = 0; jj < 4; ++jj) kv[jj] = *(const float4*)&ks[tk + 16 * jj][d0];
#pragma unroll
            for (int ii = 0; ii < 4; ++ii)
#pragma unroll
                for (int jj = 0; jj < 4; ++jj) {
                    s[ii][jj] = fmaf(qv[ii].x, kv[jj].x, s[ii][jj]);
                    s[ii][jj] = fmaf(qv[ii].y, kv[jj].y, s[ii][jj]);
                    s[ii][jj] = fmaf(qv[ii].z, kv[jj].z, s[ii][jj]);
                    s[ii][jj] = fmaf(qv[ii].w, kv[jj].w, s[ii][jj]);
                }
        }

        // penalties
#pragma unroll
        for (int jj = 0; jj < 4; ++jj) {
            const float km = kmask[tk + 16 * jj];
#pragma unroll
            for (int ii = 0; ii < 4; ++ii) {
                const float pm = pf ? (qm[ii] * km) : km;
                s[ii][jj] += (1.0f - pm) * PENf;
            }
        }

        // online softmax (row groups = 16 lanes sharing tq)
        float alpha[4];
#pragma unroll
        for (int ii = 0; ii < 4; ++ii) {
            float bm = fmaxf(fmaxf(s[ii][0], s[ii][1]), fmaxf(s[ii][2], s[ii][3]));
            bm = fmaxf(bm, __shfl_xor(bm, 1));
            bm = fmaxf(bm, __shfl_xor(bm, 2));
            bm = fmaxf(bm, __shfl_xor(bm, 4));
            bm = fmaxf(bm, __shfl_xor(bm, 8));
            const float mn = fmaxf(mrow[ii], bm);
            alpha[ii] = __expf(mrow[ii] - mn);
            mrow[ii] = mn;
            float p0 = __expf(s[ii][0] - mn);
            float p1 = __expf(s[ii][1] - mn);
            float p2 = __expf(s[ii][2] - mn);
            float p3 = __expf(s[ii][3] - mn);
            float ls = p0 + p1 + p2 + p3;
            ls += __shfl_xor(ls, 1);
            ls += __shfl_xor(ls, 2);
            ls += __shfl_xor(ls, 4);
            ls += __shfl_xor(ls, 8);
            lrow[ii] = lrow[ii] * alpha[ii] + ls;
            // store p transposed: ps[kc][qrow]
            ps[tk + 0 ][tq + 16 * ii] = p0;
            ps[tk + 16][tq + 16 * ii] = p1;
            ps[tk + 32][tq + 16 * ii] = p2;
            ps[tk + 48][tq + 16 * ii] = p3;
        }
        if (tk == 0) {
#pragma unroll
            for (int ii = 0; ii < 4; ++ii) {
                alpha_row[tq + 16 * ii] = alpha[ii];
                l_row[tq + 16 * ii] = lrow[ii];
            }
        }
        __syncthreads();

        // PV: rows (tq*4+ii), cols (tk*4+jj)
        float av[4];
#pragma unroll
        for (int ii = 0; ii < 4; ++ii) av[ii] = alpha_row[tq * 4 + ii];
#pragma unroll
        for (int ii = 0; ii < 4; ++ii) {
            accv[ii].x *= av[ii]; accv[ii].y *= av[ii];
            accv[ii].z *= av[ii]; accv[ii].w *= av[ii];
        }
#pragma unroll 4
        for (int kc = 0; kc < 64; ++kc) {
            const float4 pv = *(const float4*)&ps[kc][tq * 4];
            const float4 vv = *(const float4*)&vs[kc][tk * 4];
            accv[0] = fma4(pv.x, vv, accv[0]);
            accv[1] = fma4(pv.y, vv, accv[1]);
            accv[2] = fma4(pv.z, vv, accv[2]);
            accv[3] = fma4(pv.w, vv, accv[3]);
        }
    }

    // epilogue: divide by l, apply from_mask, write f32 (B,S,H)
#pragma unroll
    for (int ii = 0; ii < 4; ++ii) {
        const int qrow = tq * 4 + ii;
        const float fm = mask[(size_t)b * SS + (size_t)i * BS + qrow];
        const float inv = fm / l_row[qrow];
        float4 o;
        o.x = accv[ii].x * inv;
        o.y = accv[ii].y * inv;
        o.z = accv[ii].z * inv;
        o.w = accv[ii].w * inv;
        *(float4*)&out[(((size_t)b * SS) + (size_t)i * BS + qrow) * HH + h * HD + tk * 4] = o;
    }
}

extern "C" void kernel_launch(void* const* d_in, const int* in_sizes, int n_in,
                              void* d_out, int out_size, void* d_ws, size_t ws_size,
                              hipStream_t stream) {
    (void)in_sizes; (void)n_in; (void)out_size; (void)ws_size;
    const float* Q    = (const float*)d_in[0];
    const float* K    = (const float*)d_in[1];
    const float* V    = (const float*)d_in[2];
    const float* mask = (const float*)d_in[3];
    const float* Wq   = (const float*)d_in[4];
    const float* bq   = (const float*)d_in[5];
    const float* Wk   = (const float*)d_in[6];
    const float* bk   = (const float*)d_in[7];
    const float* Wv   = (const float*)d_in[8];
    const float* bv   = (const float*)d_in[9];
    const int*   ra   = (const int*)d_in[10];
    float* out = (float*)d_out;

    const size_t qkv_elems = (size_t)BB * NHh * SS * HD;  // 8.4M
    __hip_bfloat16* qb = (__hip_bfloat16*)d_ws;
    __hip_bfloat16* kb = qb + qkv_elems;
    __hip_bfloat16* vb = kb + qkv_elems;

    dim3 pgrid(128, 16);
    proj_kernel<<<pgrid, 256, 0, stream>>>(Q, Wq, bq, qb);
    proj_kernel<<<pgrid, 256, 0, stream>>>(K, Wk, bk, kb);
    proj_kernel<<<pgrid, 256, 0, stream>>>(V, Wv, bv, vb);

    attn_kernel<<<dim3(BB * NHh * LL), 256, 0, stream>>>(qb, kb, vb, mask, ra, out);
}

// Round 2
// 371.727 us; speedup vs baseline: 6.1103x; 6.1103x over previous
//
#include <hip/hip_runtime.h>
#include <hip/hip_bf16.h>
#include <stdint.h>

#define BB 2
#define SS 4096
#define HH 1024
#define NHh 16
#define HD 64
#define LL 64
#define BS 64
#define RR 3
#define PENf (-10000.0f)

typedef unsigned int uint;
typedef __attribute__((ext_vector_type(8))) short bf16x8;
typedef __attribute__((ext_vector_type(4))) float f32x4;

__device__ __forceinline__ ushort f2bf(float f) {
    union { float f; uint u; } v; v.f = f;
    uint u = v.u;
    return (ushort)((u + 0x7fffu + ((u >> 16) & 1u)) >> 16);  // RNE
}
__device__ __forceinline__ float bf2f(ushort u) {
    return __uint_as_float(((uint)u) << 16);
}
// scale both bf16 halves of a packed uint by 0.125 (exact, pow2)
__device__ __forceinline__ uint scale_pair(uint w) {
    float lo = __uint_as_float(w << 16) * 0.125f;
    float hi = __uint_as_float(w & 0xffff0000u) * 0.125f;
    return (uint)f2bf(lo) | (((uint)f2bf(hi)) << 16);
}
__device__ __forceinline__ uint4 scale4(uint4 w) {
    uint4 o;
    o.x = scale_pair(w.x); o.y = scale_pair(w.y);
    o.z = scale_pair(w.z); o.w = scale_pair(w.w);
    return o;
}
__device__ __forceinline__ uint pack_bf(float a, float b) {
    return (uint)f2bf(a) | (((uint)f2bf(b)) << 16);
}

// ---------------- fused Q/K/V projection, bf16 MFMA ----------------
// C[m][n] = sum_k X[m][k]*W[n][k] + bias[n].  128x128 tile, BK=32.
// z=0 -> qb [bh][s][hd], z=1 -> kb [bh][s][hd], z=2 -> vbT [bh][hd][s].
__global__ __launch_bounds__(256)
void proj3_kernel(const float* __restrict__ Xq, const float* __restrict__ Xk,
                  const float* __restrict__ Xv,
                  const float* __restrict__ Wq, const float* __restrict__ Wk,
                  const float* __restrict__ Wv,
                  const float* __restrict__ bq, const float* __restrict__ bk,
                  const float* __restrict__ bv,
                  ushort* __restrict__ qb, ushort* __restrict__ kb,
                  ushort* __restrict__ vbT)
{
    __shared__ __align__(16) ushort smem[128 * 136];  // 34816 B; As/Bs carved, reused as V-stage
    ushort* As = smem;             // [128][40]
    ushort* Bs = smem + 128 * 40;  // [128][40]

    const int z = blockIdx.z;
    const float* X    = (z == 0) ? Xq : (z == 1) ? Xk : Xv;
    const float* W    = (z == 0) ? Wq : (z == 1) ? Wk : Wv;
    const float* bias = (z == 0) ? bq : (z == 1) ? bk : bv;

    const int tid = threadIdx.x;
    const int m0 = blockIdx.x * 128;
    const int n0 = blockIdx.y * 128;
    const int wave = tid >> 6;
    const int lane = tid & 63;
    const int l15 = lane & 15;
    const int quad = lane >> 4;
    const int wr = wave >> 1, wc = wave & 1;

    f32x4 acc[4][4];
#pragma unroll
    for (int mt = 0; mt < 4; ++mt)
#pragma unroll
        for (int nt = 0; nt < 4; ++nt) acc[mt][nt] = (f32x4){0.f, 0.f, 0.f, 0.f};

    const int srow = tid >> 1;   // 0..127
    const int shalf = tid & 1;   // 0..1
    const float* xp = X + (size_t)(m0 + srow) * HH + shalf * 16;
    const float* wp = W + (size_t)(n0 + srow) * HH + shalf * 16;
    ushort* asw = As + srow * 40 + shalf * 16;
    ushort* bsw = Bs + srow * 40 + shalf * 16;

    for (int k0 = 0; k0 < HH; k0 += 32) {
        float4 a0 = *(const float4*)(xp + k0);
        float4 a1 = *(const float4*)(xp + k0 + 4);
        float4 a2 = *(const float4*)(xp + k0 + 8);
        float4 a3 = *(const float4*)(xp + k0 + 12);
        float4 b0 = *(const float4*)(wp + k0);
        float4 b1 = *(const float4*)(wp + k0 + 4);
        float4 b2 = *(const float4*)(wp + k0 + 8);
        float4 b3 = *(const float4*)(wp + k0 + 12);
        __syncthreads();
        uint4 pa, pb;
        pa.x = pack_bf(a0.x, a0.y); pa.y = pack_bf(a0.z, a0.w);
        pa.z = pack_bf(a1.x, a1.y); pa.w = pack_bf(a1.z, a1.w);
        *(uint4*)asw = pa;
        pa.x = pack_bf(a2.x, a2.y); pa.y = pack_bf(a2.z, a2.w);
        pa.z = pack_bf(a3.x, a3.y); pa.w = pack_bf(a3.z, a3.w);
        *(uint4*)(asw + 8) = pa;
        pb.x = pack_bf(b0.x, b0.y); pb.y = pack_bf(b0.z, b0.w);
        pb.z = pack_bf(b1.x, b1.y); pb.w = pack_bf(b1.z, b1.w);
        *(uint4*)bsw = pb;
        pb.x = pack_bf(b2.x, b2.y); pb.y = pack_bf(b2.z, b2.w);
        pb.z = pack_bf(b3.x, b3.y); pb.w = pack_bf(b3.z, b3.w);
        *(uint4*)(bsw + 8) = pb;
        __syncthreads();

        bf16x8 af[4], bfr[4];
#pragma unroll
        for (int mt = 0; mt < 4; ++mt)
            af[mt] = *(const bf16x8*)(As + (wr * 64 + mt * 16 + l15) * 40 + quad * 8);
#pragma unroll
        for (int nt = 0; nt < 4; ++nt)
            bfr[nt] = *(const bf16x8*)(Bs + (wc * 64 + nt * 16 + l15) * 40 + quad * 8);
#pragma unroll
        for (int mt = 0; mt < 4; ++mt)
#pragma unroll
            for (int nt = 0; nt < 4; ++nt)
                acc[mt][nt] = __builtin_amdgcn_mfma_f32_16x16x32_bf16(af[mt], bfr[nt], acc[mt][nt], 0, 0, 0);
    }

    if (z < 2) {
        ushort* outp = (z == 0) ? qb : kb;
#pragma unroll
        for (int nt = 0; nt < 4; ++nt) {
            const int n = n0 + wc * 64 + nt * 16 + l15;
            const float bn = bias[n];
            const int nh = n >> 6, hd = n & 63;
#pragma unroll
            for (int mt = 0; mt < 4; ++mt) {
#pragma unroll
                for (int rr = 0; rr < 4; ++rr) {
                    const int m = m0 + wr * 64 + mt * 16 + quad * 4 + rr;
                    const int bgl = m >> 12, s = m & 4095;
                    outp[((size_t)((bgl << 4) | nh) * SS + s) * HD + hd] = f2bf(acc[mt][nt][rr] + bn);
                }
            }
        }
    } else {
        // V: restage transposed in LDS, then coalesced store to vbT [bh][hd][s]
        __syncthreads();
        ushort* stg = smem;  // [128 n][136 m]
#pragma unroll
        for (int nt = 0; nt < 4; ++nt) {
            const int n_local = wc * 64 + nt * 16 + l15;
            const float bn = bias[n0 + n_local];
#pragma unroll
            for (int mt = 0; mt < 4; ++mt) {
                const int m_base = wr * 64 + mt * 16 + quad * 4;
                uint2 pk;
                pk.x = pack_bf(acc[mt][nt][0] + bn, acc[mt][nt][1] + bn);
                pk.y = pack_bf(acc[mt][nt][2] + bn, acc[mt][nt][3] + bn);
                *(uint2*)(stg + n_local * 136 + m_base) = pk;
            }
        }
        __syncthreads();
        const int n_row = tid >> 1;
        const int half = tid & 1;
        const int n = n0 + n_row;
        const int nh = n >> 6, hd = n & 63;
        const int bgl = m0 >> 12;
        const int sbase = (m0 & 4095) + half * 64;
        const uint4* src = (const uint4*)(stg + n_row * 136 + half * 64);
        uint4* dst = (uint4*)(vbT + ((size_t)((bgl << 4) | nh) * HD + hd) * SS + sbase);
#pragma unroll
        for (int j = 0; j < 8; ++j) dst[j] = src[j];
    }
}

// ---------------- block-sparse attention, bf16 MFMA ----------------
// qg/kg: bf16 [bh][s][d]; vTg: bf16 [bh][d][s]; out f32 [b][s][h*d].
// wgs: per bh, 62 "middle" wgs (i=1..62, full key list, final output) +
// 16 "dense" wgs (i in {0,63}, 8 key blocks each, write partial m/l/O).
__global__ __launch_bounds__(256)
void attn_kernel(const ushort* __restrict__ qg, const ushort* __restrict__ kg,
                 const ushort* __restrict__ vTg,
                 const float* __restrict__ mask, const int* __restrict__ rand_attn,
                 float* __restrict__ out, float* __restrict__ partO,
                 float* __restrict__ partML)
{
    __shared__ __align__(16) ushort qs[64][72];
    __shared__ __align__(16) ushort ks[64][72];
    __shared__ __align__(16) ushort vsT[64][72];
    __shared__ __align__(16) ushort ps[64][72];
    __shared__ float qm_s[64];
    __shared__ float km_s[64];

    const int tid = threadIdx.x;
    const int wid = blockIdx.x;
    const int bh = wid / 78;
    const int r = wid - bh * 78;
    const int b = bh >> 4, h = bh & 15;

    int i, nkb;
    int kbl[8], pfl[8];
    bool dense;
    int part = 0, which = 0;
    if (r < 62) {
        dense = false;
        i = r + 1;
        const int* ra = rand_attn + ((size_t)h * (LL - 2) + (i - 1)) * RR;
        if (i == 1) {
            kbl[0] = 0; kbl[1] = 1; kbl[2] = 2; kbl[3] = LL - 1;
            kbl[4] = ra[0]; kbl[5] = ra[1]; kbl[6] = ra[2]; kbl[7] = 0;
            pfl[0] = pfl[1] = pfl[2] = pfl[3] = 0;
            pfl[4] = pfl[5] = pfl[6] = 1; pfl[7] = 0;
            nkb = 7;
        } else if (i == LL - 2) {
            kbl[0] = 0; kbl[1] = LL - 3; kbl[2] = LL - 2; kbl[3] = LL - 1;
            kbl[4] = ra[0]; kbl[5] = ra[1]; kbl[6] = ra[2]; kbl[7] = 0;
            pfl[0] = pfl[1] = pfl[2] = pfl[3] = 0;
            pfl[4] = pfl[5] = pfl[6] = 1; pfl[7] = 0;
            nkb = 7;
        } else {
            kbl[0] = 0;      pfl[0] = 0;
            kbl[1] = i - 1;  pfl[1] = 1;
            kbl[2] = i;      pfl[2] = 1;
            kbl[3] = i + 1;  pfl[3] = 1;
            kbl[4] = LL - 1; pfl[4] = 0;
            kbl[5] = ra[0]; kbl[6] = ra[1]; kbl[7] = ra[2];
            pfl[5] = pfl[6] = pfl[7] = 1;
            nkb = 8;
        }
    } else {
        dense = true;
        const int r2 = r - 62;
        which = r2 >> 3;
        part = r2 & 7;
        i = which ? (LL - 1) : 0;
        nkb = 8;
#pragma unroll
        for (int j = 0; j < 8; ++j) { kbl[j] = part * 8 + j; pfl[j] = 0; }
    }

    const int lane = tid & 63;
    const int wave = tid >> 6;
    const int l15 = lane & 15;
    const int quad = lane >> 4;

    // stage q (scaled by rsd=0.125) + query mask
    {
        const int row = tid >> 2;
        const int c0 = (tid & 3) * 16;
        const ushort* src = qg + ((size_t)bh * SS + i * BS + row) * HD + c0;
        uint4 w0 = *(const uint4*)src;
        uint4 w1 = *(const uint4*)(src + 8);
        *(uint4*)&qs[row][c0] = scale4(w0);
        *(uint4*)&qs[row][c0 + 8] = scale4(w1);
        if (tid < 64) qm_s[tid] = mask[(size_t)b * SS + i * BS + tid];
    }

    float mrow[4], lrow[4];
#pragma unroll
    for (int rr = 0; rr < 4; ++rr) { mrow[rr] = -1e30f; lrow[rr] = 0.0f; }
    f32x4 accO[4];
#pragma unroll
    for (int dt = 0; dt < 4; ++dt) accO[dt] = (f32x4){0.f, 0.f, 0.f, 0.f};

    for (int it = 0; it < nkb; ++it) {
        const int kb_ = kbl[it];
        const int pf = pfl[it];
        __syncthreads();  // prev PV done; qs staged (it==0)
        {
            const int row = tid >> 2;
            const int c0 = (tid & 3) * 16;
            const ushort* srck = kg + ((size_t)bh * SS + kb_ * BS + row) * HD + c0;
            uint4 kw0 = *(const uint4*)srck;
            uint4 kw1 = *(const uint4*)(srck + 8);
            const ushort* srcv = vTg + ((size_t)bh * HD + row) * SS + kb_ * BS + c0;
            uint4 vw0 = *(const uint4*)srcv;
            uint4 vw1 = *(const uint4*)(srcv + 8);
            *(uint4*)&ks[row][c0] = kw0;
            *(uint4*)&ks[row][c0 + 8] = kw1;
            *(uint4*)&vsT[row][c0] = vw0;
            *(uint4*)&vsT[row][c0 + 8] = vw1;
            if (tid < 64) km_s[tid] = mask[(size_t)b * SS + kb_ * BS + tid];
        }
        __syncthreads();

        // scores: 1 row-tile (wave's 16 q rows) x 4 col-tiles
        f32x4 sc[4];
#pragma unroll
        for (int nt = 0; nt < 4; ++nt) sc[nt] = (f32x4){0.f, 0.f, 0.f, 0.f};
#pragma unroll
        for (int c = 0; c < 2; ++c) {
            bf16x8 aq = *(const bf16x8*)&qs[wave * 16 + l15][c * 32 + quad * 8];
#pragma unroll
            for (int nt = 0; nt < 4; ++nt) {
                bf16x8 bk_ = *(const bf16x8*)&ks[nt * 16 + l15][c * 32 + quad * 8];
                sc[nt] = __builtin_amdgcn_mfma_f32_16x16x32_bf16(aq, bk_, sc[nt], 0, 0, 0);
            }
        }

        // penalties + online softmax (row = wave*16 + quad*4 + rr)
#pragma unroll
        for (int rr = 0; rr < 4; ++rr) {
            const int qrow = wave * 16 + quad * 4 + rr;
            const float qmr = qm_s[qrow];
            float sv[4];
#pragma unroll
            for (int nt = 0; nt < 4; ++nt) {
                const float km = km_s[nt * 16 + l15];
                const float pm = pf ? (qmr * km) : km;
                sv[nt] = sc[nt][rr] + (1.0f - pm) * PENf;
            }
            float bm = fmaxf(fmaxf(sv[0], sv[1]), fmaxf(sv[2], sv[3]));
            bm = fmaxf(bm, __shfl_xor(bm, 1));
            bm = fmaxf(bm, __shfl_xor(bm, 2));
            bm = fmaxf(bm, __shfl_xor(bm, 4));
            bm = fmaxf(bm, __shfl_xor(bm, 8));
            const float mn = fmaxf(mrow[rr], bm);
            const float alpha = __expf(mrow[rr] - mn);
            mrow[rr] = mn;
            const float p0 = __expf(sv[0] - mn);
            const float p1 = __expf(sv[1] - mn);
            const float p2 = __expf(sv[2] - mn);
            const float p3 = __expf(sv[3] - mn);
            float ls = p0 + p1 + p2 + p3;
            ls += __shfl_xor(ls, 1);
            ls += __shfl_xor(ls, 2);
            ls += __shfl_xor(ls, 4);
            ls += __shfl_xor(ls, 8);
            lrow[rr] = lrow[rr] * alpha + ls;
#pragma unroll
            for (int dt = 0; dt < 4; ++dt) accO[dt][rr] *= alpha;
            ps[qrow][0 + l15]  = f2bf(p0);
            ps[qrow][16 + l15] = f2bf(p1);
            ps[qrow][32 + l15] = f2bf(p2);
            ps[qrow][48 + l15] = f2bf(p3);
        }
        __syncthreads();  // ps visible (ordering safety)

        // PV: O[16q][64d] += P[16q][64kc] * V[64kc][64d]
#pragma unroll
        for (int c = 0; c < 2; ++c) {
            bf16x8 ap = *(const bf16x8*)&ps[wave * 16 + l15][c * 32 + quad * 8];
#pragma unroll
            for (int dt = 0; dt < 4; ++dt) {
                bf16x8 bv_ = *(const bf16x8*)&vsT[dt * 16 + l15][c * 32 + quad * 8];
                accO[dt] = __builtin_amdgcn_mfma_f32_16x16x32_bf16(ap, bv_, accO[dt], 0, 0, 0);
            }
        }
    }

    if (!dense) {
#pragma unroll
        for (int rr = 0; rr < 4; ++rr) {
            const int qrow = wave * 16 + quad * 4 + rr;
            const float inv = qm_s[qrow] / lrow[rr];
#pragma unroll
            for (int dt = 0; dt < 4; ++dt) {
                const int d = dt * 16 + l15;
                out[((size_t)b * SS + i * BS + qrow) * HH + h * HD + d] = accO[dt][rr] * inv;
            }
        }
    } else {
        const int slot = (bh * 2 + which) * 8 + part;
        float* po = partO + (size_t)slot * 4096;
#pragma unroll
        for (int rr = 0; rr < 4; ++rr) {
            const int qrow = wave * 16 + quad * 4 + rr;
#pragma unroll
            for (int dt = 0; dt < 4; ++dt) {
                const int d = dt * 16 + l15;
                po[qrow * 64 + d] = accO[dt][rr];
            }
            if (l15 == 0) {
                partML[slot * 128 + qrow] = mrow[rr];
                partML[slot * 128 + 64 + qrow] = lrow[rr];
            }
        }
    }
}

// ---------------- combine partials for dense query blocks ----------------
__global__ __launch_bounds__(256)
void combine_kernel(const float* __restrict__ partO, const float* __restrict__ partML,
                    const float* __restrict__ mask, float* __restrict__ out)
{
    const int g = blockIdx.x;     // bh*2 + which
    const int bh = g >> 1, which = g & 1;
    const int b = bh >> 4, h = bh & 15;
    const int i = which ? (LL - 1) : 0;
    const int t = threadIdx.x;
    const int row = t >> 2;
    const int d0 = (t & 3) * 16;
    const int base = g * 8;

    float mp[8], lp[8];
    float M = -1e30f;
#pragma unroll
    for (int p = 0; p < 8; ++p) {
        mp[p] = partML[(base + p) * 128 + row];
        lp[p] = partML[(base + p) * 128 + 64 + row];
        M = fmaxf(M, mp[p]);
    }
    float L = 0.0f, w[8];
#pragma unroll
    for (int p = 0; p < 8; ++p) { w[p] = __expf(mp[p] - M); L += lp[p] * w[p]; }

    float4 o[4];
#pragma unroll
    for (int j = 0; j < 4; ++j) o[j] = make_float4(0.f, 0.f, 0.f, 0.f);
#pragma unroll
    for (int p = 0; p < 8; ++p) {
        const float* po = partO + (size_t)(base + p) * 4096 + row * 64 + d0;
#pragma unroll
        for (int j = 0; j < 4; ++j) {
            float4 v = *(const float4*)(po + j * 4);
            o[j].x = fmaf(w[p], v.x, o[j].x);
            o[j].y = fmaf(w[p], v.y, o[j].y);
            o[j].z = fmaf(w[p], v.z, o[j].z);
            o[j].w = fmaf(w[p], v.w, o[j].w);
        }
    }
    const float fm = mask[(size_t)b * SS + i * BS + row];
    const float inv = fm / L;
    float* dst = out + ((size_t)b * SS + i * BS + row) * HH + h * HD + d0;
#pragma unroll
    for (int j = 0; j < 4; ++j) {
        float4 v;
        v.x = o[j].x * inv; v.y = o[j].y * inv;
        v.z = o[j].z * inv; v.w = o[j].w * inv;
        *(float4*)(dst + j * 4) = v;
    }
}

extern "C" void kernel_launch(void* const* d_in, const int* in_sizes, int n_in,
                              void* d_out, int out_size, void* d_ws, size_t ws_size,
                              hipStream_t stream) {
    (void)in_sizes; (void)n_in; (void)out_size; (void)ws_size;
    const float* Q    = (const float*)d_in[0];
    const float* K    = (const float*)d_in[1];
    const float* V    = (const float*)d_in[2];
    const float* mask = (const float*)d_in[3];
    const float* Wq   = (const float*)d_in[4];
    const float* bq   = (const float*)d_in[5];
    const float* Wk   = (const float*)d_in[6];
    const float* bk   = (const float*)d_in[7];
    const float* Wv   = (const float*)d_in[8];
    const float* bv   = (const float*)d_in[9];
    const int*   ra   = (const int*)d_in[10];
    float* out = (float*)d_out;

    const size_t qkv = (size_t)BB * NHh * SS * HD;  // 8388608 elems
    ushort* qb  = (ushort*)d_ws;
    ushort* kb  = qb + qkv;
    ushort* vbT = kb + qkv;
    float* partO  = (float*)(vbT + qkv);        // 512 * 4096 f32
    float* partML = partO + (size_t)512 * 4096; // 512 * 128 f32

    proj3_kernel<<<dim3(64, 8, 3), 256, 0, stream>>>(Q, K, V, Wq, Wk, Wv, bq, bk, bv,
                                                     qb, kb, vbT);
    attn_kernel<<<dim3(BB * NHh * 78), 256, 0, stream>>>(qb, kb, vbT, mask, ra,
                                                         out, partO, partML);
    combine_kernel<<<dim3(BB * NHh * 2), 256, 0, stream>>>(partO, partML, mask, out);
}

// Round 3
// 304.505 us; speedup vs baseline: 7.4593x; 1.2208x over previous
//
#include <hip/hip_runtime.h>
#include <hip/hip_bf16.h>
#include <stdint.h>

#define BB 2
#define SS 4096
#define HH 1024
#define NHh 16
#define HD 64
#define LL 64
#define BS 64
#define RR 3
#define PENf (-10000.0f)

typedef unsigned int uint;
typedef __attribute__((ext_vector_type(8))) short bf16x8;
typedef __attribute__((ext_vector_type(4))) float f32x4;

__device__ __forceinline__ ushort f2bf(float f) {
    union { float f; uint u; } v; v.f = f;
    uint u = v.u;
    return (ushort)((u + 0x7fffu + ((u >> 16) & 1u)) >> 16);  // RNE
}
__device__ __forceinline__ uint pack_bf(float a, float b) {
    return (uint)f2bf(a) | (((uint)f2bf(b)) << 16);
}
// scale both bf16 halves of a packed uint by 0.125 (exact, pow2)
__device__ __forceinline__ uint scale_pair(uint w) {
    float lo = __uint_as_float(w << 16) * 0.125f;
    float hi = __uint_as_float(w & 0xffff0000u) * 0.125f;
    return (uint)f2bf(lo) | (((uint)f2bf(hi)) << 16);
}
__device__ __forceinline__ uint4 scale4(uint4 w) {
    uint4 o;
    o.x = scale_pair(w.x); o.y = scale_pair(w.y);
    o.z = scale_pair(w.z); o.w = scale_pair(w.w);
    return o;
}
// async global->LDS, 16B per lane; lds base must be wave-uniform (lane*16 auto)
__device__ __forceinline__ void async16(const ushort* g, ushort* l) {
    __builtin_amdgcn_global_load_lds((const __attribute__((address_space(1))) uint*)g,
                                     (__attribute__((address_space(3))) uint*)l,
                                     16, 0, 0);
}

// ---------------- fp32 -> bf16 convert (X and W) ----------------
__global__ __launch_bounds__(256)
void cvt_kernel(const float* __restrict__ Xq, const float* __restrict__ Xk,
                const float* __restrict__ Xv, const float* __restrict__ Wq,
                const float* __restrict__ Wk, const float* __restrict__ Wv,
                ushort* __restrict__ Xbf, ushort* __restrict__ Wbf)
{
    const size_t XTOT = (size_t)3 * BB * SS * HH;            // 25165824 (3 x 2^23)
    const size_t UNITS = (XTOT + (size_t)3 * HH * HH) / 8;   // 3538944
    for (size_t u = (size_t)blockIdx.x * 256 + threadIdx.x; u < UNITS;
         u += (size_t)gridDim.x * 256) {
        const size_t e = u * 8;
        const float* src; ushort* dst;
        if (e < XTOT) {
            const int zz = (int)(e >> 23);
            src = (zz == 0 ? Xq : zz == 1 ? Xk : Xv) + (e & ((1u << 23) - 1));
            dst = Xbf + e;
        } else {
            const size_t e2 = e - XTOT;
            const int zz = (int)(e2 >> 20);
            src = (zz == 0 ? Wq : zz == 1 ? Wk : Wv) + (e2 & ((1u << 20) - 1));
            dst = Wbf + e2;
        }
        float4 a = ((const float4*)src)[0];
        float4 c = ((const float4*)src)[1];
        uint4 o;
        o.x = pack_bf(a.x, a.y); o.y = pack_bf(a.z, a.w);
        o.z = pack_bf(c.x, c.y); o.w = pack_bf(c.z, c.w);
        *(uint4*)dst = o;
    }
}

// ---------------- m97-style bf16 GEMM for Q/K/V projections ----------------
// C[m][n] = sum_k A[m][k]*Bt[n][k] + bias[n]; A bf16 [8192][1024], Bt bf16 [1024][1024].
// z=0 -> qb [bh][s][hd], z=1 -> kb, z=2 -> vbT [bh][hd][s].
__global__ __launch_bounds__(256)
void gemm3_kernel(const ushort* __restrict__ Xbf, const ushort* __restrict__ Wbf,
                  const float* __restrict__ bq, const float* __restrict__ bk,
                  const float* __restrict__ bv,
                  ushort* __restrict__ qb, ushort* __restrict__ kb,
                  ushort* __restrict__ vbT)
{
    __shared__ __align__(16) ushort smem[128 * 136];  // As/Bs carved; reused for V restage
    ushort* As = smem;            // [128][32] unpadded (global_load_lds layout)
    ushort* Bs = smem + 4096;     // [128][32]

    const int z = blockIdx.z;
    const ushort* A  = Xbf + (size_t)z * ((size_t)BB * SS * HH);
    const ushort* Bt = Wbf + (size_t)z * (HH * HH);
    const float* bias = (z == 0) ? bq : (z == 1) ? bk : bv;

    const int tid = threadIdx.x;
    const int m0 = blockIdx.x * 128;
    const int n0 = blockIdx.y * 128;
    const int wave = tid >> 6;
    const int lane = tid & 63;
    const int l15 = lane & 15;
    const int quad = lane >> 4;
    const int wr = wave >> 1, wc = wave & 1;

    f32x4 acc[4][4];
#pragma unroll
    for (int mt = 0; mt < 4; ++mt)
#pragma unroll
        for (int nt = 0; nt < 4; ++nt) acc[mt][nt] = (f32x4){0.f, 0.f, 0.f, 0.f};

    const int r0 = wave * 32 + (lane >> 2);    // staging row
    const int p8 = (lane & 3) * 8;             // 16B sub-offset (elems)
    const ushort* Abase = A + (size_t)(m0 + r0) * HH + p8;
    const ushort* Bbase = Bt + (size_t)(n0 + r0) * HH + p8;
    ushort* ldsA0 = As + wave * 1024;
    ushort* ldsA1 = As + wave * 1024 + 512;
    ushort* ldsB0 = Bs + wave * 1024;
    ushort* ldsB1 = Bs + wave * 1024 + 512;

    for (int k0 = 0; k0 < HH; k0 += 32) {
        async16(Abase + k0, ldsA0);
        async16(Abase + 16 * HH + k0, ldsA1);
        async16(Bbase + k0, ldsB0);
        async16(Bbase + 16 * HH + k0, ldsB1);
        __syncthreads();  // staging visible (compiler drains vmcnt)
        bf16x8 af[4], bfr[4];
#pragma unroll
        for (int mt = 0; mt < 4; ++mt)
            af[mt] = *(const bf16x8*)(As + (wr * 64 + mt * 16 + l15) * 32 + quad * 8);
#pragma unroll
        for (int nt = 0; nt < 4; ++nt)
            bfr[nt] = *(const bf16x8*)(Bs + (wc * 64 + nt * 16 + l15) * 32 + quad * 8);
#pragma unroll
        for (int mt = 0; mt < 4; ++mt)
#pragma unroll
            for (int nt = 0; nt < 4; ++nt)
                acc[mt][nt] = __builtin_amdgcn_mfma_f32_16x16x32_bf16(af[mt], bfr[nt], acc[mt][nt], 0, 0, 0);
        __syncthreads();  // all reads done before next iter's staging
    }

    if (z < 2) {
        ushort* outp = (z == 0) ? qb : kb;
#pragma unroll
        for (int nt = 0; nt < 4; ++nt) {
            const int n = n0 + wc * 64 + nt * 16 + l15;
            const float bn = bias[n];
            const int nh = n >> 6, hd = n & 63;
#pragma unroll
            for (int mt = 0; mt < 4; ++mt) {
#pragma unroll
                for (int rr = 0; rr < 4; ++rr) {
                    const int m = m0 + wr * 64 + mt * 16 + quad * 4 + rr;
                    const int bgl = m >> 12, s = m & 4095;
                    outp[((size_t)((bgl << 4) | nh) * SS + s) * HD + hd] = f2bf(acc[mt][nt][rr] + bn);
                }
            }
        }
    } else {
        // V: restage transposed in LDS, then coalesced store to vbT [bh][hd][s]
        __syncthreads();
        ushort* stg = smem;  // [128 n][136 m]
#pragma unroll
        for (int nt = 0; nt < 4; ++nt) {
            const int n_local = wc * 64 + nt * 16 + l15;
            const float bn = bias[n0 + n_local];
#pragma unroll
            for (int mt = 0; mt < 4; ++mt) {
                const int m_base = wr * 64 + mt * 16 + quad * 4;
                uint2 pk;
                pk.x = pack_bf(acc[mt][nt][0] + bn, acc[mt][nt][1] + bn);
                pk.y = pack_bf(acc[mt][nt][2] + bn, acc[mt][nt][3] + bn);
                *(uint2*)(stg + n_local * 136 + m_base) = pk;
            }
        }
        __syncthreads();
        const int n_row = tid >> 1;
        const int half = tid & 1;
        const int n = n0 + n_row;
        const int nh = n >> 6, hd = n & 63;
        const int bgl = m0 >> 12;
        const int sbase = (m0 & 4095) + half * 64;
        const uint4* src = (const uint4*)(stg + n_row * 136 + half * 64);
        uint4* dst = (uint4*)(vbT + ((size_t)((bgl << 4) | nh) * HD + hd) * SS + sbase);
#pragma unroll
        for (int j = 0; j < 8; ++j) dst[j] = src[j];
    }
}

// ---------------- R1 fallback projection (inline convert) ----------------
__global__ __launch_bounds__(256)
void proj3_kernel(const float* __restrict__ Xq, const float* __restrict__ Xk,
                  const float* __restrict__ Xv,
                  const float* __restrict__ Wq, const float* __restrict__ Wk,
                  const float* __restrict__ Wv,
                  const float* __restrict__ bq, const float* __restrict__ bk,
                  const float* __restrict__ bv,
                  ushort* __restrict__ qb, ushort* __restrict__ kb,
                  ushort* __restrict__ vbT)
{
    __shared__ __align__(16) ushort smem[128 * 136];
    ushort* As = smem;             // [128][40]
    ushort* Bs = smem + 128 * 40;  // [128][40]

    const int z = blockIdx.z;
    const float* X    = (z == 0) ? Xq : (z == 1) ? Xk : Xv;
    const float* W    = (z == 0) ? Wq : (z == 1) ? Wk : Wv;
    const float* bias = (z == 0) ? bq : (z == 1) ? bk : bv;

    const int tid = threadIdx.x;
    const int m0 = blockIdx.x * 128;
    const int n0 = blockIdx.y * 128;
    const int wave = tid >> 6;
    const int lane = tid & 63;
    const int l15 = lane & 15;
    const int quad = lane >> 4;
    const int wr = wave >> 1, wc = wave & 1;

    f32x4 acc[4][4];
#pragma unroll
    for (int mt = 0; mt < 4; ++mt)
#pragma unroll
        for (int nt = 0; nt < 4; ++nt) acc[mt][nt] = (f32x4){0.f, 0.f, 0.f, 0.f};

    const int srow = tid >> 1;
    const int shalf = tid & 1;
    const float* xp = X + (size_t)(m0 + srow) * HH + shalf * 16;
    const float* wp = W + (size_t)(n0 + srow) * HH + shalf * 16;
    ushort* asw = As + srow * 40 + shalf * 16;
    ushort* bsw = Bs + srow * 40 + shalf * 16;

    for (int k0 = 0; k0 < HH; k0 += 32) {
        float4 a0 = *(const float4*)(xp + k0);
        float4 a1 = *(const float4*)(xp + k0 + 4);
        float4 a2 = *(const float4*)(xp + k0 + 8);
        float4 a3 = *(const float4*)(xp + k0 + 12);
        float4 b0 = *(const float4*)(wp + k0);
        float4 b1 = *(const float4*)(wp + k0 + 4);
        float4 b2 = *(const float4*)(wp + k0 + 8);
        float4 b3 = *(const float4*)(wp + k0 + 12);
        __syncthreads();
        uint4 pa, pb;
        pa.x = pack_bf(a0.x, a0.y); pa.y = pack_bf(a0.z, a0.w);
        pa.z = pack_bf(a1.x, a1.y); pa.w = pack_bf(a1.z, a1.w);
        *(uint4*)asw = pa;
        pa.x = pack_bf(a2.x, a2.y); pa.y = pack_bf(a2.z, a2.w);
        pa.z = pack_bf(a3.x, a3.y); pa.w = pack_bf(a3.z, a3.w);
        *(uint4*)(asw + 8) = pa;
        pb.x = pack_bf(b0.x, b0.y); pb.y = pack_bf(b0.z, b0.w);
        pb.z = pack_bf(b1.x, b1.y); pb.w = pack_bf(b1.z, b1.w);
        *(uint4*)bsw = pb;
        pb.x = pack_bf(b2.x, b2.y); pb.y = pack_bf(b2.z, b2.w);
        pb.z = pack_bf(b3.x, b3.y); pb.w = pack_bf(b3.z, b3.w);
        *(uint4*)(bsw + 8) = pb;
        __syncthreads();

        bf16x8 af[4], bfr[4];
#pragma unroll
        for (int mt = 0; mt < 4; ++mt)
            af[mt] = *(const bf16x8*)(As + (wr * 64 + mt * 16 + l15) * 40 + quad * 8);
#pragma unroll
        for (int nt = 0; nt < 4; ++nt)
            bfr[nt] = *(const bf16x8*)(Bs + (wc * 64 + nt * 16 + l15) * 40 + quad * 8);
#pragma unroll
        for (int mt = 0; mt < 4; ++mt)
#pragma unroll
            for (int nt = 0; nt < 4; ++nt)
                acc[mt][nt] = __builtin_amdgcn_mfma_f32_16x16x32_bf16(af[mt], bfr[nt], acc[mt][nt], 0, 0, 0);
    }

    if (z < 2) {
        ushort* outp = (z == 0) ? qb : kb;
#pragma unroll
        for (int nt = 0; nt < 4; ++nt) {
            const int n = n0 + wc * 64 + nt * 16 + l15;
            const float bn = bias[n];
            const int nh = n >> 6, hd = n & 63;
#pragma unroll
            for (int mt = 0; mt < 4; ++mt) {
#pragma unroll
                for (int rr = 0; rr < 4; ++rr) {
                    const int m = m0 + wr * 64 + mt * 16 + quad * 4 + rr;
                    const int bgl = m >> 12, s = m & 4095;
                    outp[((size_t)((bgl << 4) | nh) * SS + s) * HD + hd] = f2bf(acc[mt][nt][rr] + bn);
                }
            }
        }
    } else {
        __syncthreads();
        ushort* stg = smem;
#pragma unroll
        for (int nt = 0; nt < 4; ++nt) {
            const int n_local = wc * 64 + nt * 16 + l15;
            const float bn = bias[n0 + n_local];
#pragma unroll
            for (int mt = 0; mt < 4; ++mt) {
                const int m_base = wr * 64 + mt * 16 + quad * 4;
                uint2 pk;
                pk.x = pack_bf(acc[mt][nt][0] + bn, acc[mt][nt][1] + bn);
                pk.y = pack_bf(acc[mt][nt][2] + bn, acc[mt][nt][3] + bn);
                *(uint2*)(stg + n_local * 136 + m_base) = pk;
            }
        }
        __syncthreads();
        const int n_row = tid >> 1;
        const int half = tid & 1;
        const int n = n0 + n_row;
        const int nh = n >> 6, hd = n & 63;
        const int bgl = m0 >> 12;
        const int sbase = (m0 & 4095) + half * 64;
        const uint4* src = (const uint4*)(stg + n_row * 136 + half * 64);
        uint4* dst = (uint4*)(vbT + ((size_t)((bgl << 4) | nh) * HD + hd) * SS + sbase);
#pragma unroll
        for (int j = 0; j < 8; ++j) dst[j] = src[j];
    }
}

// ---------------- block-sparse attention, S^T orientation ----------------
// qg/kg bf16 [bh][s][d]; vTg bf16 [bh][d][s]; out f32 [b][s][h*d].
__global__ __launch_bounds__(256)
void attn_kernel(const ushort* __restrict__ qg, const ushort* __restrict__ kg,
                 const ushort* __restrict__ vTg,
                 const float* __restrict__ mask, const int* __restrict__ rand_attn,
                 float* __restrict__ out, float* __restrict__ partO,
                 float* __restrict__ partML)
{
    __shared__ __align__(16) ushort qs[64][72];
    __shared__ __align__(16) ushort ks2[2][64][32];   // [k-chunk][kc][d-chunk 32]
    __shared__ __align__(16) ushort vs2[2][64][32];   // [kc-chunk][d][kc 32]
    __shared__ __align__(16) ushort ps[64][72];       // wave-private 16-row bands
    __shared__ __align__(16) float qm_s[64];
    __shared__ __align__(16) float km_s[64];

    const int tid = threadIdx.x;
    const int wid = blockIdx.x;
    const int bh = wid / 78;
    const int r = wid - bh * 78;
    const int b = bh >> 4, h = bh & 15;

    int i, nkb;
    int kbl[8], pfl[8];
    bool dense;
    int part = 0, which = 0;
    if (r < 62) {
        dense = false;
        i = r + 1;
        const int* ra = rand_attn + ((size_t)h * (LL - 2) + (i - 1)) * RR;
        if (i == 1) {
            kbl[0] = 0; kbl[1] = 1; kbl[2] = 2; kbl[3] = LL - 1;
            kbl[4] = ra[0]; kbl[5] = ra[1]; kbl[6] = ra[2]; kbl[7] = 0;
            pfl[0] = pfl[1] = pfl[2] = pfl[3] = 0;
            pfl[4] = pfl[5] = pfl[6] = 1; pfl[7] = 0;
            nkb = 7;
        } else if (i == LL - 2) {
            kbl[0] = 0; kbl[1] = LL - 3; kbl[2] = LL - 2; kbl[3] = LL - 1;
            kbl[4] = ra[0]; kbl[5] = ra[1]; kbl[6] = ra[2]; kbl[7] = 0;
            pfl[0] = pfl[1] = pfl[2] = pfl[3] = 0;
            pfl[4] = pfl[5] = pfl[6] = 1; pfl[7] = 0;
            nkb = 7;
        } else {
            kbl[0] = 0;      pfl[0] = 0;
            kbl[1] = i - 1;  pfl[1] = 1;
            kbl[2] = i;      pfl[2] = 1;
            kbl[3] = i + 1;  pfl[3] = 1;
            kbl[4] = LL - 1; pfl[4] = 0;
            kbl[5] = ra[0]; kbl[6] = ra[1]; kbl[7] = ra[2];
            pfl[5] = pfl[6] = pfl[7] = 1;
            nkb = 8;
        }
    } else {
        dense = true;
        const int r2 = r - 62;
        which = r2 >> 3;
        part = r2 & 7;
        i = which ? (LL - 1) : 0;
        nkb = 8;
#pragma unroll
        for (int j = 0; j < 8; ++j) { kbl[j] = part * 8 + j; pfl[j] = 0; }
    }

    const int lane = tid & 63;
    const int wave = tid >> 6;
    const int l15 = lane & 15;
    const int quad = lane >> 4;

    // stage q (scaled by rsd) + query mask
    {
        const int row = tid >> 2;
        const int c0 = (tid & 3) * 16;
        const ushort* src = qg + ((size_t)bh * SS + i * BS + row) * HD + c0;
        uint4 w0 = *(const uint4*)src;
        uint4 w1 = *(const uint4*)(src + 8);
        *(uint4*)&qs[row][c0] = scale4(w0);
        *(uint4*)&qs[row][c0 + 8] = scale4(w1);
        if (tid < 64) qm_s[tid] = mask[(size_t)b * SS + i * BS + tid];
    }
    __syncthreads();
    // hoist q fragments (B-operand, n = q = wave*16 + l15) and this lane's q-mask
    bf16x8 aq[2];
    aq[0] = *(const bf16x8*)&qs[wave * 16 + l15][quad * 8];
    aq[1] = *(const bf16x8*)&qs[wave * 16 + l15][32 + quad * 8];
    const float qm = qm_s[wave * 16 + l15];

    float mrow = -1e30f, lrow = 0.0f;   // per-lane, q = wave*16 + l15
    f32x4 accO[4];
#pragma unroll
    for (int dt = 0; dt < 4; ++dt) accO[dt] = (f32x4){0.f, 0.f, 0.f, 0.f};

    const int srow = lane >> 2;
    const int p8 = (lane & 3) * 8;
    const ushort* kgb = kg + (size_t)bh * SS * HD;
    const ushort* vgb = vTg + (size_t)bh * HD * SS;

    for (int it = 0; it < nkb; ++it) {
        const int kb_ = kbl[it];
        const int pf = pfl[it];
        __syncthreads();  // prev iter's frag reads done before restaging
        {
            const size_t krow = (size_t)(kb_ * BS + wave * 16 + srow) * HD;
            async16(kgb + krow + p8,      &ks2[0][wave * 16][0]);
            async16(kgb + krow + 32 + p8, &ks2[1][wave * 16][0]);
            const size_t vrow = (size_t)(wave * 16 + srow) * SS + kb_ * BS;
            async16(vgb + vrow + p8,      &vs2[0][wave * 16][0]);
            async16(vgb + vrow + 32 + p8, &vs2[1][wave * 16][0]);
            if (tid < 64) km_s[tid] = mask[(size_t)b * SS + kb_ * BS + tid];
        }
        __syncthreads();  // staging visible

        // S^T = K . Q^T : A = K rows (m=kc), B = Q rows (n=q)
        f32x4 sc[4];
#pragma unroll
        for (int nt = 0; nt < 4; ++nt) sc[nt] = (f32x4){0.f, 0.f, 0.f, 0.f};
#pragma unroll
        for (int c = 0; c < 2; ++c) {
#pragma unroll
            for (int nt = 0; nt < 4; ++nt) {
                bf16x8 af = *(const bf16x8*)&ks2[c][nt * 16 + l15][quad * 8];
                sc[nt] = __builtin_amdgcn_mfma_f32_16x16x32_bf16(af, aq[c], sc[nt], 0, 0, 0);
            }
        }

        // penalties: lane holds (q = wave*16+l15, kc = nt*16+quad*4+rr)
        float p[4][4];
        float bm = -1e30f;
#pragma unroll
        for (int nt = 0; nt < 4; ++nt) {
            const float4 km4 = *(const float4*)&km_s[nt * 16 + quad * 4];
            const float kmv[4] = {km4.x, km4.y, km4.z, km4.w};
#pragma unroll
            for (int rr = 0; rr < 4; ++rr) {
                const float pm = pf ? (qm * kmv[rr]) : kmv[rr];
                const float sv = sc[nt][rr] + (1.0f - pm) * PENf;
                p[nt][rr] = sv;
                bm = fmaxf(bm, sv);
            }
        }
        // reduce over kc: in-lane (16 vals) done; across quads = xor 16, 32
        bm = fmaxf(bm, __shfl_xor(bm, 16));
        bm = fmaxf(bm, __shfl_xor(bm, 32));
        const float mn = fmaxf(mrow, bm);
        const float alpha = __expf(mrow - mn);
        mrow = mn;
        float ls = 0.0f;
#pragma unroll
        for (int nt = 0; nt < 4; ++nt)
#pragma unroll
            for (int rr = 0; rr < 4; ++rr) {
                p[nt][rr] = __expf(p[nt][rr] - mn);
                ls += p[nt][rr];
            }
        ls += __shfl_xor(ls, 16);
        ls += __shfl_xor(ls, 32);
        lrow = lrow * alpha + ls;

        // write P (bf16) into wave-private ps rows; b64 stores
#pragma unroll
        for (int nt = 0; nt < 4; ++nt) {
            uint2 pk;
            pk.x = pack_bf(p[nt][0], p[nt][1]);
            pk.y = pack_bf(p[nt][2], p[nt][3]);
            *(uint2*)&ps[wave * 16 + l15][nt * 16 + quad * 4] = pk;
        }
        // broadcast alpha to accO's row domain (q_local = quad*4+rr)
        float a4[4];
#pragma unroll
        for (int rr = 0; rr < 4; ++rr) a4[rr] = __shfl(alpha, quad * 4 + rr, 64);
#pragma unroll
        for (int dt = 0; dt < 4; ++dt) {
#pragma unroll
            for (int rr = 0; rr < 4; ++rr) accO[dt][rr] *= a4[rr];
        }

        // PV: A = ps (m=q), B = vs2 (n=d); no barrier needed (ps wave-private)
#pragma unroll
        for (int c = 0; c < 2; ++c) {
            bf16x8 ap = *(const bf16x8*)&ps[wave * 16 + l15][c * 32 + quad * 8];
#pragma unroll
            for (int dt = 0; dt < 4; ++dt) {
                bf16x8 bvf = *(const bf16x8*)&vs2[c][dt * 16 + l15][quad * 8];
                accO[dt] = __builtin_amdgcn_mfma_f32_16x16x32_bf16(ap, bvf, accO[dt], 0, 0, 0);
            }
        }
    }

    if (!dense) {
#pragma unroll
        for (int rr = 0; rr < 4; ++rr) {
            const int qloc = quad * 4 + rr;
            const float lq = __shfl(lrow, qloc, 64);
            const float inv = qm_s[wave * 16 + qloc] / lq;
#pragma unroll
            for (int dt = 0; dt < 4; ++dt) {
                const int d = dt * 16 + l15;
                out[((size_t)b * SS + i * BS + wave * 16 + qloc) * HH + h * HD + d] = accO[dt][rr] * inv;
            }
        }
    } else {
        const int slot = (bh * 2 + which) * 8 + part;
        float* po = partO + (size_t)slot * 4096;
#pragma unroll
        for (int rr = 0; rr < 4; ++rr) {
            const int qrow = wave * 16 + quad * 4 + rr;
#pragma unroll
            for (int dt = 0; dt < 4; ++dt) {
                const int d = dt * 16 + l15;
                po[qrow * 64 + d] = accO[dt][rr];
            }
        }
        if (lane < 16) {
            partML[slot * 128 + wave * 16 + lane] = mrow;
            partML[slot * 128 + 64 + wave * 16 + lane] = lrow;
        }
    }
}

// ---------------- combine partials for dense query blocks ----------------
__global__ __launch_bounds__(256)
void combine_kernel(const float* __restrict__ partO, const float* __restrict__ partML,
                    const float* __restrict__ mask, float* __restrict__ out)
{
    const int g = blockIdx.x;     // bh*2 + which
    const int bh = g >> 1, which = g & 1;
    const int b = bh >> 4, h = bh & 15;
    const int i = which ? (LL - 1) : 0;
    const int t = threadIdx.x;
    const int row = t >> 2;
    const int d0 = (t & 3) * 16;
    const int base = g * 8;

    float mp[8], lp[8];
    float M = -1e30f;
#pragma unroll
    for (int p = 0; p < 8; ++p) {
        mp[p] = partML[(base + p) * 128 + row];
        lp[p] = partML[(base + p) * 128 + 64 + row];
        M = fmaxf(M, mp[p]);
    }
    float L = 0.0f, w[8];
#pragma unroll
    for (int p = 0; p < 8; ++p) { w[p] = __expf(mp[p] - M); L += lp[p] * w[p]; }

    float4 o[4];
#pragma unroll
    for (int j = 0; j < 4; ++j) o[j] = make_float4(0.f, 0.f, 0.f, 0.f);
#pragma unroll
    for (int p = 0; p < 8; ++p) {
        const float* po = partO + (size_t)(base + p) * 4096 + row * 64 + d0;
#pragma unroll
        for (int j = 0; j < 4; ++j) {
            float4 v = *(const float4*)(po + j * 4);
            o[j].x = fmaf(w[p], v.x, o[j].x);
            o[j].y = fmaf(w[p], v.y, o[j].y);
            o[j].z = fmaf(w[p], v.z, o[j].z);
            o[j].w = fmaf(w[p], v.w, o[j].w);
        }
    }
    const float fm = mask[(size_t)b * SS + i * BS + row];
    const float inv = fm / L;
    float* dst = out + ((size_t)b * SS + i * BS + row) * HH + h * HD + d0;
#pragma unroll
    for (int j = 0; j < 4; ++j) {
        float4 v;
        v.x = o[j].x * inv; v.y = o[j].y * inv;
        v.z = o[j].z * inv; v.w = o[j].w * inv;
        *(float4*)(dst + j * 4) = v;
    }
}

extern "C" void kernel_launch(void* const* d_in, const int* in_sizes, int n_in,
                              void* d_out, int out_size, void* d_ws, size_t ws_size,
                              hipStream_t stream) {
    (void)in_sizes; (void)n_in; (void)out_size;
    const float* Q    = (const float*)d_in[0];
    const float* K    = (const float*)d_in[1];
    const float* V    = (const float*)d_in[2];
    const float* mask = (const float*)d_in[3];
    const float* Wq   = (const float*)d_in[4];
    const float* bq   = (const float*)d_in[5];
    const float* Wk   = (const float*)d_in[6];
    const float* bk   = (const float*)d_in[7];
    const float* Wv   = (const float*)d_in[8];
    const float* bv   = (const float*)d_in[9];
    const int*   ra   = (const int*)d_in[10];
    float* out = (float*)d_out;

    const size_t qkv = (size_t)BB * NHh * SS * HD;  // 8388608 elems
    ushort* qb  = (ushort*)d_ws;
    ushort* kb  = qb + qkv;
    ushort* vbT = kb + qkv;
    float* partO  = (float*)(vbT + qkv);            // 512 * 4096 f32
    float* partML = partO + (size_t)512 * 4096;     // 512 * 128 f32
    ushort* Xbf = (ushort*)(partML + (size_t)512 * 128);
    ushort* Wbf = Xbf + 3 * qkv;
    const size_t need = (size_t)((char*)(Wbf + (size_t)3 * HH * HH) - (char*)d_ws);

    if (ws_size >= need) {
        cvt_kernel<<<4096, 256, 0, stream>>>(Q, K, V, Wq, Wk, Wv, Xbf, Wbf);
        gemm3_kernel<<<dim3(64, 8, 3), 256, 0, stream>>>(Xbf, Wbf, bq, bk, bv, qb, kb, vbT);
    } else {
        proj3_kernel<<<dim3(64, 8, 3), 256, 0, stream>>>(Q, K, V, Wq, Wk, Wv, bq, bk, bv,
                                                         qb, kb, vbT);
    }
    attn_kernel<<<dim3(BB * NHh * 78), 256, 0, stream>>>(qb, kb, vbT, mask, ra,
                                                         out, partO, partML);
    combine_kernel<<<dim3(BB * NHh * 2), 256, 0, stream>>>(partO, partML, mask, out);
}

// Round 4
// 303.505 us; speedup vs baseline: 7.4838x; 1.0033x over previous
//
#include <hip/hip_runtime.h>
#include <hip/hip_bf16.h>
#include <stdint.h>

#define BB 2
#define SS 4096
#define HH 1024
#define NHh 16
#define HD 64
#define LL 64
#define BS 64
#define RR 3
#define PENf (-10000.0f)

typedef unsigned int uint;
typedef __attribute__((ext_vector_type(8))) short bf16x8;
typedef __attribute__((ext_vector_type(4))) float f32x4;

__device__ __forceinline__ ushort f2bf(float f) {
    union { float f; uint u; } v; v.f = f;
    uint u = v.u;
    return (ushort)((u + 0x7fffu + ((u >> 16) & 1u)) >> 16);  // RNE
}
__device__ __forceinline__ uint pack_bf(float a, float b) {
    return (uint)f2bf(a) | (((uint)f2bf(b)) << 16);
}
// scale both bf16 halves of a packed uint by 0.125 (exact, pow2)
__device__ __forceinline__ uint scale_pair(uint w) {
    float lo = __uint_as_float(w << 16) * 0.125f;
    float hi = __uint_as_float(w & 0xffff0000u) * 0.125f;
    return (uint)f2bf(lo) | (((uint)f2bf(hi)) << 16);
}
__device__ __forceinline__ uint4 scale4(uint4 w) {
    uint4 o;
    o.x = scale_pair(w.x); o.y = scale_pair(w.y);
    o.z = scale_pair(w.z); o.w = scale_pair(w.w);
    return o;
}
// async global->LDS, 16B per lane; lds base must be wave-uniform (lane*16 auto)
__device__ __forceinline__ void async16(const ushort* g, ushort* l) {
    __builtin_amdgcn_global_load_lds((const __attribute__((address_space(1))) uint*)g,
                                     (__attribute__((address_space(3))) uint*)l,
                                     16, 0, 0);
}

// ---------------- fp32 -> bf16 convert (X and W), exact grid ----------------
// grid = 13824 blocks x 256: 12288 X-blocks then 1536 W-blocks (uniform branch).
__global__ __launch_bounds__(256)
void cvt_kernel(const float* __restrict__ Xq, const float* __restrict__ Xk,
                const float* __restrict__ Xv, const float* __restrict__ Wq,
                const float* __restrict__ Wk, const float* __restrict__ Wv,
                ushort* __restrict__ Xbf, ushort* __restrict__ Wbf)
{
    const size_t XTOT = (size_t)3 * BB * SS * HH;   // 25165824 = 3 * 2^23
    const uint u = blockIdx.x * 256 + threadIdx.x;
    const size_t e = (size_t)u * 8;
    const float* src; ushort* dst;
    if (e < XTOT) {
        const int zz = (int)(e >> 23);
        src = (zz == 0 ? Xq : zz == 1 ? Xk : Xv) + (e & ((1u << 23) - 1));
        dst = Xbf + e;
    } else {
        const size_t e2 = e - XTOT;
        const int zz = (int)(e2 >> 20);
        src = (zz == 0 ? Wq : zz == 1 ? Wk : Wv) + (e2 & ((1u << 20) - 1));
        dst = Wbf + e2;
    }
    float4 a = ((const float4*)src)[0];
    float4 c = ((const float4*)src)[1];
    uint4 o;
    o.x = pack_bf(a.x, a.y); o.y = pack_bf(a.z, a.w);
    o.z = pack_bf(c.x, c.y); o.w = pack_bf(c.z, c.w);
    *(uint4*)dst = o;
}

// ---------------- m97-style bf16 GEMM, dbuf + swapped epilogue ----------------
// C[m][n] = sum_k A[m][k]*Bt[n][k] + bias[n]; A bf16 [8192][1024], Bt bf16 [1024][1024].
// z=0 -> qb [bh][s][hd], z=1 -> kb, z=2 -> vbT [bh][hd][s].
// z<2 computes D with m=W-row (hd) so each lane's 4 regs = 4 consecutive hd -> b64 stores.
__global__ __launch_bounds__(256)
void gemm3_kernel(const ushort* __restrict__ Xbf, const ushort* __restrict__ Wbf,
                  const float* __restrict__ bq, const float* __restrict__ bk,
                  const float* __restrict__ bv,
                  ushort* __restrict__ qb, ushort* __restrict__ kb,
                  ushort* __restrict__ vbT)
{
    __shared__ __align__(16) ushort smem[128 * 136];  // dbuf As/Bs (16K elems) + V restage reuse
    ushort* As = smem;            // [2][128][32]
    ushort* Bs = smem + 8192;     // [2][128][32]

    const int z = blockIdx.z;
    const ushort* A  = Xbf + (size_t)z * ((size_t)BB * SS * HH);
    const ushort* Bt = Wbf + (size_t)z * (HH * HH);
    const float* bias = (z == 0) ? bq : (z == 1) ? bk : bv;

    const int tid = threadIdx.x;
    const int m0 = blockIdx.x * 128;
    const int n0 = blockIdx.y * 128;
    const int wave = tid >> 6;
    const int lane = tid & 63;
    const int l15 = lane & 15;
    const int quad = lane >> 4;
    const int wr = wave >> 1, wc = wave & 1;

    f32x4 acc[4][4];
#pragma unroll
    for (int i = 0; i < 4; ++i)
#pragma unroll
        for (int j = 0; j < 4; ++j) acc[i][j] = (f32x4){0.f, 0.f, 0.f, 0.f};

    const int p8 = (lane & 3) * 8;             // 16B sub-offset (elems)
    const ushort* Abase = A + (size_t)(m0 + wave * 32 + (lane >> 2)) * HH + p8;
    const ushort* Bbase = Bt + (size_t)(n0 + wave * 32 + (lane >> 2)) * HH + p8;

#define STAGE_G(k0, bp)                                        \
    do {                                                       \
        ushort* A0 = As + (bp) * 4096 + wave * 1024;           \
        ushort* B0 = Bs + (bp) * 4096 + wave * 1024;           \
        async16(Abase + (k0), A0);                             \
        async16(Abase + 16 * HH + (k0), A0 + 512);             \
        async16(Bbase + (k0), B0);                             \
        async16(Bbase + 16 * HH + (k0), B0 + 512);             \
    } while (0)

    STAGE_G(0, 0);
    for (int k0 = 0, bp = 0; k0 < HH; k0 += 32, bp ^= 1) {
        __syncthreads();  // publish buf bp; all reads of bp^1 done
        if (k0 + 32 < HH) STAGE_G(k0 + 32, bp ^ 1);
        bf16x8 af[4], bfr[4];
#pragma unroll
        for (int mt = 0; mt < 4; ++mt)
            af[mt] = *(const bf16x8*)(As + bp * 4096 + (wr * 64 + mt * 16 + l15) * 32 + quad * 8);
#pragma unroll
        for (int nt = 0; nt < 4; ++nt)
            bfr[nt] = *(const bf16x8*)(Bs + bp * 4096 + (wc * 64 + nt * 16 + l15) * 32 + quad * 8);
        if (z < 2) {
#pragma unroll
            for (int i = 0; i < 4; ++i)
#pragma unroll
                for (int j = 0; j < 4; ++j)
                    acc[i][j] = __builtin_amdgcn_mfma_f32_16x16x32_bf16(bfr[i], af[j], acc[i][j], 0, 0, 0);
        } else {
#pragma unroll
            for (int i = 0; i < 4; ++i)
#pragma unroll
                for (int j = 0; j < 4; ++j)
                    acc[i][j] = __builtin_amdgcn_mfma_f32_16x16x32_bf16(af[i], bfr[j], acc[i][j], 0, 0, 0);
        }
    }
#undef STAGE_G

    if (z < 2) {
        // acc[wt][xt]: D row = W-row-local (wc*64+wt*16+quad*4+rr), col = X-row-local (wr*64+xt*16+l15)
        ushort* outp = (z == 0) ? qb : kb;
#pragma unroll
        for (int wt = 0; wt < 4; ++wt) {
            const int n_base = n0 + wc * 64 + wt * 16 + quad * 4;   // 4 consecutive n (hd)
            const float4 b4 = *(const float4*)&bias[n_base];
            const int nh = n_base >> 6;
            const int hd = n_base & 63;
#pragma unroll
            for (int xt = 0; xt < 4; ++xt) {
                const int m = m0 + wr * 64 + xt * 16 + l15;
                const int bgl = m >> 12, s = m & 4095;
                uint2 pk;
                pk.x = pack_bf(acc[wt][xt][0] + b4.x, acc[wt][xt][1] + b4.y);
                pk.y = pack_bf(acc[wt][xt][2] + b4.z, acc[wt][xt][3] + b4.w);
                *(uint2*)&outp[((size_t)((bgl << 4) | nh) * SS + s) * HD + hd] = pk;
            }
        }
    } else {
        // V: restage transposed in LDS, then coalesced store to vbT [bh][hd][s]
        __syncthreads();
        ushort* stg = smem;  // [128 n][136 m]
#pragma unroll
        for (int nt = 0; nt < 4; ++nt) {
            const int n_local = wc * 64 + nt * 16 + l15;
            const float bn = bias[n0 + n_local];
#pragma unroll
            for (int mt = 0; mt < 4; ++mt) {
                const int m_base = wr * 64 + mt * 16 + quad * 4;
                uint2 pk;
                pk.x = pack_bf(acc[mt][nt][0] + bn, acc[mt][nt][1] + bn);
                pk.y = pack_bf(acc[mt][nt][2] + bn, acc[mt][nt][3] + bn);
                *(uint2*)(stg + n_local * 136 + m_base) = pk;
            }
        }
        __syncthreads();
        const int n_row = tid >> 1;
        const int half = tid & 1;
        const int n = n0 + n_row;
        const int nh = n >> 6, hd = n & 63;
        const int bgl = m0 >> 12;
        const int sbase = (m0 & 4095) + half * 64;
        const uint4* src = (const uint4*)(stg + n_row * 136 + half * 64);
        uint4* dst = (uint4*)(vbT + ((size_t)((bgl << 4) | nh) * HD + hd) * SS + sbase);
#pragma unroll
        for (int j = 0; j < 8; ++j) dst[j] = src[j];
    }
}

// ---------------- R1 fallback projection (inline convert) ----------------
__global__ __launch_bounds__(256)
void proj3_kernel(const float* __restrict__ Xq, const float* __restrict__ Xk,
                  const float* __restrict__ Xv,
                  const float* __restrict__ Wq, const float* __restrict__ Wk,
                  const float* __restrict__ Wv,
                  const float* __restrict__ bq, const float* __restrict__ bk,
                  const float* __restrict__ bv,
                  ushort* __restrict__ qb, ushort* __restrict__ kb,
                  ushort* __restrict__ vbT)
{
    __shared__ __align__(16) ushort smem[128 * 136];
    ushort* As = smem;             // [128][40]
    ushort* Bs = smem + 128 * 40;  // [128][40]

    const int z = blockIdx.z;
    const float* X    = (z == 0) ? Xq : (z == 1) ? Xk : Xv;
    const float* W    = (z == 0) ? Wq : (z == 1) ? Wk : Wv;
    const float* bias = (z == 0) ? bq : (z == 1) ? bk : bv;

    const int tid = threadIdx.x;
    const int m0 = blockIdx.x * 128;
    const int n0 = blockIdx.y * 128;
    const int wave = tid >> 6;
    const int lane = tid & 63;
    const int l15 = lane & 15;
    const int quad = lane >> 4;
    const int wr = wave >> 1, wc = wave & 1;

    f32x4 acc[4][4];
#pragma unroll
    for (int mt = 0; mt < 4; ++mt)
#pragma unroll
        for (int nt = 0; nt < 4; ++nt) acc[mt][nt] = (f32x4){0.f, 0.f, 0.f, 0.f};

    const int srow = tid >> 1;
    const int shalf = tid & 1;
    const float* xp = X + (size_t)(m0 + srow) * HH + shalf * 16;
    const float* wp = W + (size_t)(n0 + srow) * HH + shalf * 16;
    ushort* asw = As + srow * 40 + shalf * 16;
    ushort* bsw = Bs + srow * 40 + shalf * 16;

    for (int k0 = 0; k0 < HH; k0 += 32) {
        float4 a0 = *(const float4*)(xp + k0);
        float4 a1 = *(const float4*)(xp + k0 + 4);
        float4 a2 = *(const float4*)(xp + k0 + 8);
        float4 a3 = *(const float4*)(xp + k0 + 12);
        float4 b0 = *(const float4*)(wp + k0);
        float4 b1 = *(const float4*)(wp + k0 + 4);
        float4 b2 = *(const float4*)(wp + k0 + 8);
        float4 b3 = *(const float4*)(wp + k0 + 12);
        __syncthreads();
        uint4 pa, pb;
        pa.x = pack_bf(a0.x, a0.y); pa.y = pack_bf(a0.z, a0.w);
        pa.z = pack_bf(a1.x, a1.y); pa.w = pack_bf(a1.z, a1.w);
        *(uint4*)asw = pa;
        pa.x = pack_bf(a2.x, a2.y); pa.y = pack_bf(a2.z, a2.w);
        pa.z = pack_bf(a3.x, a3.y); pa.w = pack_bf(a3.z, a3.w);
        *(uint4*)(asw + 8) = pa;
        pb.x = pack_bf(b0.x, b0.y); pb.y = pack_bf(b0.z, b0.w);
        pb.z = pack_bf(b1.x, b1.y); pb.w = pack_bf(b1.z, b1.w);
        *(uint4*)bsw = pb;
        pb.x = pack_bf(b2.x, b2.y); pb.y = pack_bf(b2.z, b2.w);
        pb.z = pack_bf(b3.x, b3.y); pb.w = pack_bf(b3.z, b3.w);
        *(uint4*)(bsw + 8) = pb;
        __syncthreads();

        bf16x8 af[4], bfr[4];
#pragma unroll
        for (int mt = 0; mt < 4; ++mt)
            af[mt] = *(const bf16x8*)(As + (wr * 64 + mt * 16 + l15) * 40 + quad * 8);
#pragma unroll
        for (int nt = 0; nt < 4; ++nt)
            bfr[nt] = *(const bf16x8*)(Bs + (wc * 64 + nt * 16 + l15) * 40 + quad * 8);
#pragma unroll
        for (int mt = 0; mt < 4; ++mt)
#pragma unroll
            for (int nt = 0; nt < 4; ++nt)
                acc[mt][nt] = __builtin_amdgcn_mfma_f32_16x16x32_bf16(af[mt], bfr[nt], acc[mt][nt], 0, 0, 0);
    }

    if (z < 2) {
        ushort* outp = (z == 0) ? qb : kb;
#pragma unroll
        for (int nt = 0; nt < 4; ++nt) {
            const int n = n0 + wc * 64 + nt * 16 + l15;
            const float bn = bias[n];
            const int nh = n >> 6, hd = n & 63;
#pragma unroll
            for (int mt = 0; mt < 4; ++mt) {
#pragma unroll
                for (int rr = 0; rr < 4; ++rr) {
                    const int m = m0 + wr * 64 + mt * 16 + quad * 4 + rr;
                    const int bgl = m >> 12, s = m & 4095;
                    outp[((size_t)((bgl << 4) | nh) * SS + s) * HD + hd] = f2bf(acc[mt][nt][rr] + bn);
                }
            }
        }
    } else {
        __syncthreads();
        ushort* stg = smem;
#pragma unroll
        for (int nt = 0; nt < 4; ++nt) {
            const int n_local = wc * 64 + nt * 16 + l15;
            const float bn = bias[n0 + n_local];
#pragma unroll
            for (int mt = 0; mt < 4; ++mt) {
                const int m_base = wr * 64 + mt * 16 + quad * 4;
                uint2 pk;
                pk.x = pack_bf(acc[mt][nt][0] + bn, acc[mt][nt][1] + bn);
                pk.y = pack_bf(acc[mt][nt][2] + bn, acc[mt][nt][3] + bn);
                *(uint2*)(stg + n_local * 136 + m_base) = pk;
            }
        }
        __syncthreads();
        const int n_row = tid >> 1;
        const int half = tid & 1;
        const int n = n0 + n_row;
        const int nh = n >> 6, hd = n & 63;
        const int bgl = m0 >> 12;
        const int sbase = (m0 & 4095) + half * 64;
        const uint4* src = (const uint4*)(stg + n_row * 136 + half * 64);
        uint4* dst = (uint4*)(vbT + ((size_t)((bgl << 4) | nh) * HD + hd) * SS + sbase);
#pragma unroll
        for (int j = 0; j < 8; ++j) dst[j] = src[j];
    }
}

// ---------------- block-sparse attention, S^T + dbuf single-barrier ----------------
// qg/kg bf16 [bh][s][d]; vTg bf16 [bh][d][s]; out f32 [b][s][h*d].
__global__ __launch_bounds__(256)
void attn_kernel(const ushort* __restrict__ qg, const ushort* __restrict__ kg,
                 const ushort* __restrict__ vTg,
                 const float* __restrict__ mask, const int* __restrict__ rand_attn,
                 float* __restrict__ out, float* __restrict__ partO,
                 float* __restrict__ partML)
{
    __shared__ __align__(16) ushort qs_ps[64][72];      // q staging, then ps (wave-private bands)
    __shared__ __align__(16) ushort ks2[2][2][64][32];  // [buf][k-chunk][kc][d32]
    __shared__ __align__(16) ushort vs2[2][2][64][32];  // [buf][kc-chunk][d][kc32]
    __shared__ __align__(16) float qm_s[64];
    __shared__ __align__(16) float km_s[2][64];

    const int tid = threadIdx.x;
    const int wid = blockIdx.x;
    const int bh = wid / 78;
    const int r = wid - bh * 78;
    const int b = bh >> 4, h = bh & 15;

    int i, nkb;
    int kbl[8], pfl[8];
    bool dense;
    int part = 0, which = 0;
    if (r < 62) {
        dense = false;
        i = r + 1;
        const int* ra = rand_attn + ((size_t)h * (LL - 2) + (i - 1)) * RR;
        if (i == 1) {
            kbl[0] = 0; kbl[1] = 1; kbl[2] = 2; kbl[3] = LL - 1;
            kbl[4] = ra[0]; kbl[5] = ra[1]; kbl[6] = ra[2]; kbl[7] = 0;
            pfl[0] = pfl[1] = pfl[2] = pfl[3] = 0;
            pfl[4] = pfl[5] = pfl[6] = 1; pfl[7] = 0;
            nkb = 7;
        } else if (i == LL - 2) {
            kbl[0] = 0; kbl[1] = LL - 3; kbl[2] = LL - 2; kbl[3] = LL - 1;
            kbl[4] = ra[0]; kbl[5] = ra[1]; kbl[6] = ra[2]; kbl[7] = 0;
            pfl[0] = pfl[1] = pfl[2] = pfl[3] = 0;
            pfl[4] = pfl[5] = pfl[6] = 1; pfl[7] = 0;
            nkb = 7;
        } else {
            kbl[0] = 0;      pfl[0] = 0;
            kbl[1] = i - 1;  pfl[1] = 1;
            kbl[2] = i;      pfl[2] = 1;
            kbl[3] = i + 1;  pfl[3] = 1;
            kbl[4] = LL - 1; pfl[4] = 0;
            kbl[5] = ra[0]; kbl[6] = ra[1]; kbl[7] = ra[2];
            pfl[5] = pfl[6] = pfl[7] = 1;
            nkb = 8;
        }
    } else {
        dense = true;
        const int r2 = r - 62;
        which = r2 >> 3;
        part = r2 & 7;
        i = which ? (LL - 1) : 0;
        nkb = 8;
#pragma unroll
        for (int j = 0; j < 8; ++j) { kbl[j] = part * 8 + j; pfl[j] = 0; }
    }

    const int lane = tid & 63;
    const int wave = tid >> 6;
    const int l15 = lane & 15;
    const int quad = lane >> 4;
    const int srow = lane >> 2;
    const int p8 = (lane & 3) * 8;
    const ushort* kgb = kg + (size_t)bh * SS * HD;
    const ushort* vgb = vTg + (size_t)bh * HD * SS;

#define STAGE_KV(kb_, bp)                                                        \
    do {                                                                         \
        const size_t krow = (size_t)((kb_) * BS + wave * 16 + srow) * HD;        \
        async16(kgb + krow + p8,      &ks2[bp][0][wave * 16][0]);                \
        async16(kgb + krow + 32 + p8, &ks2[bp][1][wave * 16][0]);                \
        const size_t vrow = (size_t)(wave * 16 + srow) * SS + (kb_) * BS;        \
        async16(vgb + vrow + p8,      &vs2[bp][0][wave * 16][0]);                \
        async16(vgb + vrow + 32 + p8, &vs2[bp][1][wave * 16][0]);                \
    } while (0)

    // stage q (scaled by rsd) + masks + first K/V buffer
    {
        const int row = tid >> 2;
        const int c0 = (tid & 3) * 16;
        const ushort* src = qg + ((size_t)bh * SS + i * BS + row) * HD + c0;
        uint4 w0 = *(const uint4*)src;
        uint4 w1 = *(const uint4*)(src + 8);
        *(uint4*)&qs_ps[row][c0] = scale4(w0);
        *(uint4*)&qs_ps[row][c0 + 8] = scale4(w1);
        if (tid < 64) qm_s[tid] = mask[(size_t)b * SS + i * BS + tid];
    }
    STAGE_KV(kbl[0], 0);
    if (tid < 64) km_s[0][tid] = mask[(size_t)b * SS + kbl[0] * BS + tid];
    __syncthreads();  // publish qs, buf0, masks

    // hoist q fragments (B-operand, n=q=wave*16+l15); qs region becomes ps after this
    bf16x8 aq[2];
    aq[0] = *(const bf16x8*)&qs_ps[wave * 16 + l15][quad * 8];
    aq[1] = *(const bf16x8*)&qs_ps[wave * 16 + l15][32 + quad * 8];
    const float qm = qm_s[wave * 16 + l15];

    float mrow = -1e30f, lrow = 0.0f;   // per-lane, q = wave*16 + l15
    f32x4 accO[4];
#pragma unroll
    for (int dt = 0; dt < 4; ++dt) accO[dt] = (f32x4){0.f, 0.f, 0.f, 0.f};

    for (int it = 0; it < nkb; ++it) {
        const int cur = it & 1;
        if (it + 1 < nkb) {
            STAGE_KV(kbl[it + 1], cur ^ 1);   // flies during this iter's compute
            if (tid < 64) km_s[cur ^ 1][tid] = mask[(size_t)b * SS + kbl[it + 1] * BS + tid];
        }
        const int pf = pfl[it];

        // S^T = K . Q^T : A = K rows (m=kc), B = Q rows (n=q)
        f32x4 sc[4];
#pragma unroll
        for (int nt = 0; nt < 4; ++nt) sc[nt] = (f32x4){0.f, 0.f, 0.f, 0.f};
#pragma unroll
        for (int c = 0; c < 2; ++c) {
#pragma unroll
            for (int nt = 0; nt < 4; ++nt) {
                bf16x8 af = *(const bf16x8*)&ks2[cur][c][nt * 16 + l15][quad * 8];
                sc[nt] = __builtin_amdgcn_mfma_f32_16x16x32_bf16(af, aq[c], sc[nt], 0, 0, 0);
            }
        }

        // penalties: lane holds (q = wave*16+l15, kc = nt*16+quad*4+rr)
        float p[4][4];
        float bm = -1e30f;
#pragma unroll
        for (int nt = 0; nt < 4; ++nt) {
            const float4 km4 = *(const float4*)&km_s[cur][nt * 16 + quad * 4];
            const float kmv[4] = {km4.x, km4.y, km4.z, km4.w};
#pragma unroll
            for (int rr = 0; rr < 4; ++rr) {
                const float pm = pf ? (qm * kmv[rr]) : kmv[rr];
                const float sv = sc[nt][rr] + (1.0f - pm) * PENf;
                p[nt][rr] = sv;
                bm = fmaxf(bm, sv);
            }
        }
        bm = fmaxf(bm, __shfl_xor(bm, 16));
        bm = fmaxf(bm, __shfl_xor(bm, 32));
        const float mn = fmaxf(mrow, bm);
        const float alpha = __expf(mrow - mn);
        mrow = mn;
        float ls = 0.0f;
#pragma unroll
        for (int nt = 0; nt < 4; ++nt)
#pragma unroll
            for (int rr = 0; rr < 4; ++rr) {
                p[nt][rr] = __expf(p[nt][rr] - mn);
                ls += p[nt][rr];
            }
        ls += __shfl_xor(ls, 16);
        ls += __shfl_xor(ls, 32);
        lrow = lrow * alpha + ls;

        // write P (bf16) into wave-private ps rows; b64 stores
#pragma unroll
        for (int nt = 0; nt < 4; ++nt) {
            uint2 pk;
            pk.x = pack_bf(p[nt][0], p[nt][1]);
            pk.y = pack_bf(p[nt][2], p[nt][3]);
            *(uint2*)&qs_ps[wave * 16 + l15][nt * 16 + quad * 4] = pk;
        }
        // broadcast alpha to accO's row domain (q_local = quad*4+rr)
        float a4[4];
#pragma unroll
        for (int rr = 0; rr < 4; ++rr) a4[rr] = __shfl(alpha, quad * 4 + rr, 64);
#pragma unroll
        for (int dt = 0; dt < 4; ++dt) {
#pragma unroll
            for (int rr = 0; rr < 4; ++rr) accO[dt][rr] *= a4[rr];
        }

        // PV: A = ps (m=q), B = vs2 (n=d); ps is wave-private -> no barrier
#pragma unroll
        for (int c = 0; c < 2; ++c) {
            bf16x8 ap = *(const bf16x8*)&qs_ps[wave * 16 + l15][c * 32 + quad * 8];
#pragma unroll
            for (int dt = 0; dt < 4; ++dt) {
                bf16x8 bvf = *(const bf16x8*)&vs2[cur][c][dt * 16 + l15][quad * 8];
                accO[dt] = __builtin_amdgcn_mfma_f32_16x16x32_bf16(ap, bvf, accO[dt], 0, 0, 0);
            }
        }

        if (it + 1 < nkb) __syncthreads();  // publish buf cur^1; protect buf reuse
    }
#undef STAGE_KV

    if (!dense) {
#pragma unroll
        for (int rr = 0; rr < 4; ++rr) {
            const int qloc = quad * 4 + rr;
            const float lq = __shfl(lrow, qloc, 64);
            const float inv = qm_s[wave * 16 + qloc] / lq;
#pragma unroll
            for (int dt = 0; dt < 4; ++dt) {
                const int d = dt * 16 + l15;
                out[((size_t)b * SS + i * BS + wave * 16 + qloc) * HH + h * HD + d] = accO[dt][rr] * inv;
            }
        }
    } else {
        const int slot = (bh * 2 + which) * 8 + part;
        float* po = partO + (size_t)slot * 4096;
#pragma unroll
        for (int rr = 0; rr < 4; ++rr) {
            const int qrow = wave * 16 + quad * 4 + rr;
#pragma unroll
            for (int dt = 0; dt < 4; ++dt) {
                const int d = dt * 16 + l15;
                po[qrow * 64 + d] = accO[dt][rr];
            }
        }
        if (lane < 16) {
            partML[slot * 128 + wave * 16 + lane] = mrow;
            partML[slot * 128 + 64 + wave * 16 + lane] = lrow;
        }
    }
}

// ---------------- combine partials for dense query blocks ----------------
__global__ __launch_bounds__(256)
void combine_kernel(const float* __restrict__ partO, const float* __restrict__ partML,
                    const float* __restrict__ mask, float* __restrict__ out)
{
    const int g = blockIdx.x;     // bh*2 + which
    const int bh = g >> 1, which = g & 1;
    const int b = bh >> 4, h = bh & 15;
    const int i = which ? (LL - 1) : 0;
    const int t = threadIdx.x;
    const int row = t >> 2;
    const int d0 = (t & 3) * 16;
    const int base = g * 8;

    float mp[8], lp[8];
    float M = -1e30f;
#pragma unroll
    for (int p = 0; p < 8; ++p) {
        mp[p] = partML[(base + p) * 128 + row];
        lp[p] = partML[(base + p) * 128 + 64 + row];
        M = fmaxf(M, mp[p]);
    }
    float L = 0.0f, w[8];
#pragma unroll
    for (int p = 0; p < 8; ++p) { w[p] = __expf(mp[p] - M); L += lp[p] * w[p]; }

    float4 o[4];
#pragma unroll
    for (int j = 0; j < 4; ++j) o[j] = make_float4(0.f, 0.f, 0.f, 0.f);
#pragma unroll
    for (int p = 0; p < 8; ++p) {
        const float* po = partO + (size_t)(base + p) * 4096 + row * 64 + d0;
#pragma unroll
        for (int j = 0; j < 4; ++j) {
            float4 v = *(const float4*)(po + j * 4);
            o[j].x = fmaf(w[p], v.x, o[j].x);
            o[j].y = fmaf(w[p], v.y, o[j].y);
            o[j].z = fmaf(w[p], v.z, o[j].z);
            o[j].w = fmaf(w[p], v.w, o[j].w);
        }
    }
    const float fm = mask[(size_t)b * SS + i * BS + row];
    const float inv = fm / L;
    float* dst = out + ((size_t)b * SS + i * BS + row) * HH + h * HD + d0;
#pragma unroll
    for (int j = 0; j < 4; ++j) {
        float4 v;
        v.x = o[j].x * inv; v.y = o[j].y * inv;
        v.z = o[j].z * inv; v.w = o[j].w * inv;
        *(float4*)(dst + j * 4) = v;
    }
}

extern "C" void kernel_launch(void* const* d_in, const int* in_sizes, int n_in,
                              void* d_out, int out_size, void* d_ws, size_t ws_size,
                              hipStream_t stream) {
    (void)in_sizes; (void)n_in; (void)out_size;
    const float* Q    = (const float*)d_in[0];
    const float* K    = (const float*)d_in[1];
    const float* V    = (const float*)d_in[2];
    const float* mask = (const float*)d_in[3];
    const float* Wq   = (const float*)d_in[4];
    const float* bq   = (const float*)d_in[5];
    const float* Wk   = (const float*)d_in[6];
    const float* bk   = (const float*)d_in[7];
    const float* Wv   = (const float*)d_in[8];
    const float* bv   = (const float*)d_in[9];
    const int*   ra   = (const int*)d_in[10];
    float* out = (float*)d_out;

    const size_t qkv = (size_t)BB * NHh * SS * HD;  // 8388608 elems
    ushort* qb  = (ushort*)d_ws;
    ushort* kb  = qb + qkv;
    ushort* vbT = kb + qkv;
    float* partO  = (float*)(vbT + qkv);            // 512 * 4096 f32
    float* partML = partO + (size_t)512 * 4096;     // 512 * 128 f32
    ushort* Xbf = (ushort*)(partML + (size_t)512 * 128);
    ushort* Wbf = Xbf + 3 * qkv;
    const size_t need = (size_t)((char*)(Wbf + (size_t)3 * HH * HH) - (char*)d_ws);

    if (ws_size >= need) {
        cvt_kernel<<<13824, 256, 0, stream>>>(Q, K, V, Wq, Wk, Wv, Xbf, Wbf);
        gemm3_kernel<<<dim3(64, 8, 3), 256, 0, stream>>>(Xbf, Wbf, bq, bk, bv, qb, kb, vbT);
    } else {
        proj3_kernel<<<dim3(64, 8, 3), 256, 0, stream>>>(Q, K, V, Wq, Wk, Wv, bq, bk, bv,
                                                         qb, kb, vbT);
    }
    attn_kernel<<<dim3(BB * NHh * 78), 256, 0, stream>>>(qb, kb, vbT, mask, ra,
                                                         out, partO, partML);
    combine_kernel<<<dim3(BB * NHh * 2), 256, 0, stream>>>(partO, partML, mask, out);
}